// Round 33
// baseline (74.018 us; speedup 1.0000x reference)
//
#include <hip/hip_runtime.h>
#include <hip/hip_bf16.h>

#define B_    2
#define CIN_  5
#define H_    160
#define W_    160
#define N_    25600        // H*W
#define D_    48
#define NW_   32
#define WS_   800
#define HEADS_ 3
#define DH_   24
#define INNER_ 72
#define NWH_  192          // B*NW*HEADS

typedef __bf16 bf16x8 __attribute__((ext_vector_type(8)));
typedef float  f32x4  __attribute__((ext_vector_type(4)));

#define MFMA(a,b,c) __builtin_amdgcn_mfma_f32_16x16x32_bf16((a),(b),(c),0,0,0)

__device__ __forceinline__ float fast_exp2(float x) {
#if __has_builtin(__builtin_amdgcn_exp2f)
    return __builtin_amdgcn_exp2f(x);
#else
    return exp2f(x);
#endif
}

__device__ __forceinline__ unsigned pack_bf16(float lo, float hi) {
    __bf16 l = (__bf16)lo, h = (__bf16)hi;
    unsigned short ul = __builtin_bit_cast(unsigned short, l);
    unsigned short uh = __builtin_bit_cast(unsigned short, h);
    return ((unsigned)uh << 16) | (unsigned)ul;
}

// ---------------- K0: weight prep -> padded/reordered bf16 (+ e/f diag) ----------------
__global__ __launch_bounds__(256) void k_wprep(const float* __restrict__ wqkv,
                                               const float* __restrict__ w_out,
                                               const float* __restrict__ fw1,
                                               const float* __restrict__ fw2,
                                               const float* __restrict__ wfin,
                                               const float* __restrict__ cw,
                                               const float* __restrict__ Em,
                                               const float* __restrict__ Fm,
                                               const float* __restrict__ we,
                                               const float* __restrict__ be,
                                               const float* __restrict__ wf,
                                               const float* __restrict__ bf,
                                               float* __restrict__ diag,
                                               __bf16* __restrict__ wqB,   // [288][64]
                                               __bf16* __restrict__ woB,   // [48][96]
                                               __bf16* __restrict__ f1B,   // [48][64]
                                               __bf16* __restrict__ f2B,   // [48][64]
                                               __bf16* __restrict__ wfB,   // [96][64]
                                               __bf16* __restrict__ wcB) { // [48][64]
    if (blockIdx.x == 0 && threadIdx.x < 72) {
        int tt = threadIdx.x;
        int h = tt / 24, d = tt % 24;
        float se = be[d], sf = bf[d];
        for (int w = 0; w < 30; ++w) {
            se += Em[(h*24+d)*30 + w] * we[d*30 + w];
            sf += Fm[(h*24+d)*30 + w] * wf[d*30 + w];
        }
        diag[tt]      = se;
        diag[72 + tt] = sf;
    }
    int t = blockIdx.x*256 + threadIdx.x, stride = gridDim.x*256;
    for (int i = t; i < 288*64; i += stride) {
        int grow = i>>6, c = i&63;
        int gg = grow>>5, q = grow&31, tt = q>>4, sp = q&15, d = tt*16+sp;
        int part = gg/3, head = gg%3;
        wqB[i] = (d<24 && c<48) ? (__bf16)wqkv[(head*72 + part*24 + d)*48 + c] : (__bf16)0.f;
    }
    for (int i = t; i < 48*96;  i += stride) {
        int o = i/96, p = i%96;
        int h = p>>5, q = p&31, j = q&1, sp = q>>1, d = j*16+sp;
        woB[i] = (d<24) ? (__bf16)w_out[o*72 + h*24 + d] : (__bf16)0.f;
    }
    for (int i = t; i < 48*64;  i += stride) { int o=i>>6, c=i&63; f1B[i] = (c<48)? (__bf16)fw1[o*48+c] : (__bf16)0.f; }
    for (int i = t; i < 48*64;  i += stride) { int o=i>>6, c=i&63; f2B[i] = (c<48)? (__bf16)fw2[o*48+c] : (__bf16)0.f; }
    for (int i = t; i < 96*64;  i += stride) { int o=i>>6, c=i&63; wfB[i] = (c<48)? (__bf16)wfin[o*48+c] : (__bf16)0.f; }
    for (int i = t; i < 48*64;  i += stride) { int o=i>>6, c=i&63; wcB[i] = (c<45)? (__bf16)cw[o*45+c] : (__bf16)0.f; }
}

// ---------------- K1: fused conv+LN1+QKV, 32-row blocks, 4-way group split ----------------
// 32 | 160 -> no image-row wrap: 3 halo rows, 34 guard cols (2 KB Lx), bounds-free gather.
// Waves 0-1: conv 16 rows each + LN. QKV: 9 groups over 4 waves (2/2/3/2).
// Pre-barrier: ALL waves issue first-group weight + diag loads (independent of conv);
// wave 3 also writes the constant Vt pad rows -> idle conv-phase waves do useful work.
__global__ __launch_bounds__(256) void k_cqkv(const float* __restrict__ x,
                                              const __bf16* __restrict__ wcB,
                                              const float* __restrict__ cb,
                                              const float* __restrict__ pa,
                                              const __bf16* __restrict__ wqB,
                                              const float* __restrict__ g1,
                                              const float* __restrict__ b1,
                                              const float* __restrict__ diag,
                                              float* __restrict__ seqT,
                                              __bf16* __restrict__ Qbf,
                                              __bf16* __restrict__ Kbf,
                                              __bf16* __restrict__ Vt) {
    __shared__ float Lx[CIN_][3][34];          // 2 KB: 3 halo rows, 32+2 guard cols
    __shared__ __bf16 xfer[32*64];             // 4 KB: 32 rows x 64 cols, swizzled
    int t = threadIdx.x;                       // 0..255
    int blk = blockIdx.x;                      // 0..1599
    int b = blk / 800;
    int n0 = (blk % 800) * 32;                 // pixel index within image
    int y0 = n0 / W_;                          // exact row (no wrap: 32 | 160)
    int x0 = n0 % W_;

    // ---- cooperative x staging: rows y0-1..y0+1, cols x0-1..x0+32, zeros outside ----
    for (int i = t; i < CIN_*3*34; i += 256) {
        int ic = i / (3*34), rem = i % (3*34), yy = rem / 34, col = rem % 34;
        int yr = y0 - 1 + yy;
        int xc = x0 - 1 + col;
        float v = 0.f;
        if (yr >= 0 && yr < H_ && xc >= 0 && xc < W_)
            v = x[((size_t)(b*CIN_ + ic)*H_ + yr)*W_ + xc];
        Lx[ic][yy][col] = v;
    }

    int wv = t >> 6, lane = t & 63, g = lane>>4, s = lane&15;
    char* xb = (char*)xfer;

    // ---- pre-barrier: QKV-phase setup, independent of conv ----
    int w = n0 / WS_, i0 = n0 % WS_;           // 32 | 800: block stays in one window
    size_t headbase = (size_t)((b*NW_ + w)*HEADS_);
    const bf16x8* WQ4 = (const bf16x8*)wqB;
    int gg0 = (wv < 3) ? wv*2 : 7;
    int gg1 = (wv == 2) ? 7 : gg0 + 2;
    // first-group weights in flight during conv phase
    bf16x8 we0 = WQ4[(gg0*32 +      s)*8 +     g];
    bf16x8 we1 = WQ4[(gg0*32 +      s)*8 + 4 + g];
    bf16x8 wo0 = WQ4[(gg0*32 + 16 + s)*8 +     g];
    bf16x8 wo1 = WQ4[(gg0*32 + 16 + s)*8 + 4 + g];
    float dke[3], dko[3], dve[3], dvo[3];
    #pragma unroll
    for (int h = 0; h < 3; ++h) {
        dke[h] = diag[h*24 + s];
        dko[h] = (s < 8) ? diag[h*24 + 16 + s] : 0.f;
        dve[h] = diag[72 + h*24 + s];
        dvo[h] = (s < 8) ? diag[72 + h*24 + 16 + s] : 0.f;
    }
    // Vt pad rows 24..31 (ones at 24): wave 3, overlapped with conv phase
    if (wv == 3) {
        unsigned* Vd = (unsigned*)Vt;
        #pragma unroll
        for (int it = 0; it < 6; ++it) {
            int idx = it*64 + lane;           // 0..383
            int h = idx >> 7, rem = idx & 127;
            int dd = 24 + (rem >> 4), cp = rem & 15;
            size_t ubase = (((headbase + h)*((size_t)32*WS_) + (size_t)dd*WS_ + i0) >> 1);
            Vd[ubase + cp] = (dd == 24) ? 0x3F803F80u : 0u;
        }
    }
    __syncthreads();                           // Lx ready

    // ---- conv phase: waves 0-1 own 16 rows each; waves 2-3 wait ----
    if (wv < 2) {
        int rloc0 = wv * 16;
        int rib = rloc0 + s;                   // row in block = pixel offset
        bf16x8 ac[2];
        #pragma unroll
        for (int kc = 0; kc < 2; ++kc) {
            int kbase = kc*32 + g*8;
            #pragma unroll
            for (int j = 0; j < 8; ++j) {
                int k = kbase + j;
                int ic = k / 9, rem = k % 9, ky = rem / 3, kx = rem % 3;
                float v = 0.f;
                if (kc == 0 || k < 45)
                    v = Lx[ic][ky][rib + kx];  // guard cols absorb edges
                ac[kc][j] = (__bf16)v;
            }
        }
        const bf16x8* WC4 = (const bf16x8*)wcB;
        float a = pa[0];
        float cbv[3], g1v[3], b1v[3];
        #pragma unroll
        for (int n = 0; n < 3; ++n) {
            cbv[n] = cb[n*16+s]; g1v[n] = g1[n*16+s]; b1v[n] = b1[n*16+s];
        }
        float xr[3][4];
        #pragma unroll
        for (int n = 0; n < 3; ++n) {
            bf16x8 wb0 = WC4[(n*16+s)*8 + g];
            bf16x8 wb1 = WC4[(n*16+s)*8 + 4 + g];
            f32x4 c = {0.f,0.f,0.f,0.f};
            c = MFMA(ac[0], wb0, c);
            c = MFMA(ac[1], wb1, c);
            #pragma unroll
            for (int r = 0; r < 4; ++r) {
                float vv = c[r] + cbv[n];
                vv = vv >= 0.f ? vv : a * vv;
                xr[n][r] = vv;
            }
        }
        int grow0 = blk*32 + rloc0;
        #pragma unroll
        for (int n = 0; n < 3; ++n)
          #pragma unroll
          for (int r = 0; r < 4; ++r)
            seqT[(size_t)(grow0 + g*4 + r)*48 + n*16 + s] = xr[n][r];

        // LN per row -> xfer (swizzled); row&7 == (g*4+r)&7 since rloc0 % 16 == 0
        #pragma unroll
        for (int r = 0; r < 4; ++r) {
            float sm = xr[0][r] + xr[1][r] + xr[2][r];
            float sq = xr[0][r]*xr[0][r] + xr[1][r]*xr[1][r] + xr[2][r]*xr[2][r];
            #pragma unroll
            for (int msk = 1; msk < 16; msk <<= 1) { sm += __shfl_xor(sm, msk); sq += __shfl_xor(sq, msk); }
            float mean = sm * (1.f/48.f);
            float var  = sq * (1.f/48.f) - mean*mean;
            float rs   = rsqrtf(var + 1e-5f);
            int row = rloc0 + g*4 + r;
            int sw  = ((g*4+r)&7) << 4;
            #pragma unroll
            for (int n = 0; n < 3; ++n) {
                float yn = (xr[n][r] - mean) * rs * g1v[n] + b1v[n];
                *(__bf16*)(xb + ((row*128 + (n*16+s)*2) ^ sw)) = (__bf16)yn;
            }
            *(__bf16*)(xb + ((row*128 + (48+s)*2) ^ sw)) = (__bf16)0.f;  // K-pad
        }
    }
    __syncthreads();

    // ---- QKV phase: 9 groups over 4 waves: {0,1} {2,3} {4,5,6} {7,8} ----
    bf16x8 af[2][2];
    #pragma unroll
    for (int m = 0; m < 2; ++m)
      #pragma unroll
      for (int kc = 0; kc < 2; ++kc) {
        int row = m*16 + s;
        af[m][kc] = *(const bf16x8*)(xb + ((row*128 + kc*64 + g*16) ^ ((s&7)<<4)));
      }

    // 24^-0.5 * log2(e): fold attention scale AND exp2 conversion into Q
    const float SCALE = 0.2944889919f;

    unsigned* Qd = (unsigned*)Qbf;
    unsigned* Kd = (unsigned*)Kbf;

    for (int gg = gg0; gg < gg1; ++gg) {
        int part = gg / 3, head = gg % 3;
        if (gg != gg0) {                       // first group preloaded pre-barrier
            we0 = WQ4[(gg*32 +      s)*8 +     g];
            we1 = WQ4[(gg*32 +      s)*8 + 4 + g];
            wo0 = WQ4[(gg*32 + 16 + s)*8 +     g];
            wo1 = WQ4[(gg*32 + 16 + s)*8 + 4 + g];
        }
        f32x4 ce[2], co[2];
        __builtin_amdgcn_s_setprio(1);
        #pragma unroll
        for (int m = 0; m < 2; ++m) {
            f32x4 c = {0.f,0.f,0.f,0.f};
            c = MFMA(af[m][0], we0, c); c = MFMA(af[m][1], we1, c);
            ce[m] = c;
            f32x4 d = {0.f,0.f,0.f,0.f};
            d = MFMA(af[m][0], wo0, d); d = MFMA(af[m][1], wo1, d);
            co[m] = d;
        }
        __builtin_amdgcn_s_setprio(0);
        size_t rbase = (headbase + head)*WS_ + i0;
        if (part == 0) {
            #pragma unroll
            for (int m = 0; m < 2; ++m)
              #pragma unroll
              for (int r = 0; r < 4; ++r)
                Qd[(rbase + m*16 + g*4 + r)*16 + s] =
                    pack_bf16(ce[m][r]*SCALE, co[m][r]*SCALE);
        } else if (part == 1) {
            #pragma unroll
            for (int m = 0; m < 2; ++m)
              #pragma unroll
              for (int r = 0; r < 4; ++r) {
                int p5 = 16*(g&1) + 8*m + 4*(g>>1) + r;
                Kd[(rbase + p5)*16 + s] =
                    pack_bf16(ce[m][r]*dke[head], co[m][r]*dko[head]);
              }
        } else {
            // V: each lane's 4 r-values are CONSECUTIVE in Vt's n-dim -> one 8B store
            size_t vbase = (headbase + head)*((size_t)32*WS_) + i0;
            #pragma unroll
            for (int m = 0; m < 2; ++m) {
                uint2 pe;
                pe.x = pack_bf16(ce[m][0]*dve[head], ce[m][1]*dve[head]);
                pe.y = pack_bf16(ce[m][2]*dve[head], ce[m][3]*dve[head]);
                *(uint2*)&Vt[vbase + (size_t)s*WS_ + m*16 + g*4] = pe;
                if (s < 8) {
                    uint2 po;
                    po.x = pack_bf16(co[m][0]*dvo[head], co[m][1]*dvo[head]);
                    po.y = pack_bf16(co[m][2]*dvo[head], co[m][3]*dvo[head]);
                    *(uint2*)&Vt[vbase + (size_t)(16+s)*WS_ + m*16 + g*4] = po;
                }
            }
        }
    }
}

// ---------------- K3: MFMA attention, register-resident P, split-K wave pairs ----------------
// 2-way split + bijective XCD-chunked block swizzle + setprio around MFMA cluster (T5).
__global__ __launch_bounds__(256, 4) void k_attn(const __bf16* __restrict__ Qbf,
                                                 const __bf16* __restrict__ Kbf,
                                                 const __bf16* __restrict__ Vt,
                                                 __bf16* __restrict__ OW) {
    __shared__ float red[2][5][2][4][64];      // 20 KB
    int t = threadIdx.x;
    int wv = t >> 6, lane = t & 63;
    int g = lane >> 4, s = lane & 15;
    int half = wv & 1, tsk = wv >> 1;
    int blk = blockIdx.x;                      // 0..959
    int v = (blk & 7) * 120 + (blk >> 3);      // XCD-chunked bijection
    int task = v * 2 + tsk;                    // 0..1919 exactly
    int wh = task / 10, qt = task % 10;
    int q0 = qt * 80;

    const bf16x8* Qp = (const bf16x8*)(Qbf + ((size_t)wh*WS_ + q0)*32);
    const bf16x8* Kp = (const bf16x8*)(Kbf + (size_t)wh*WS_*32);
    const bf16x8* Vp = (const bf16x8*)(Vt  + (size_t)wh*32*WS_);

    // Q as B-operand: col = query = lane&15
    bf16x8 qb[5];
    #pragma unroll
    for (int i = 0; i < 5; ++i) qb[i] = Qp[(i*16 + s)*4 + g];

    f32x4 o[5][2];
    #pragma unroll
    for (int i = 0; i < 5; ++i) {
        o[i][0] = (f32x4){0.f,0.f,0.f,0.f};
        o[i][1] = (f32x4){0.f,0.f,0.f,0.f};
    }

    // combining wave (half 0) gets one chunk less: 12 vs 13
    int c0 = half ? 12 : 0;
    int c1 = half ? 25 : 12;

    // prefetch first chunk
    bf16x8 ka0 = Kp[(c0*32 + s)*4 + g];
    bf16x8 ka1 = Kp[(c0*32 + 16 + s)*4 + g];
    bf16x8 vb0 = Vp[s*100 + c0*4 + g];
    bf16x8 vb1 = Vp[(16+s)*100 + c0*4 + g];

    for (int c = c0; c < c1; ++c) {
        int cn = (c + 1 < c1) ? c + 1 : c0;    // last-iter reload is harmless
        bf16x8 nk0 = Kp[(cn*32 + s)*4 + g];
        bf16x8 nk1 = Kp[(cn*32 + 16 + s)*4 + g];
        bf16x8 nv0 = Vp[s*100 + cn*4 + g];
        bf16x8 nv1 = Vp[(16+s)*100 + cn*4 + g];

        __builtin_amdgcn_s_setprio(1);
        #pragma unroll
        for (int i = 0; i < 5; ++i) {
            f32x4 s0 = {0.f,0.f,0.f,0.f}, s1 = {0.f,0.f,0.f,0.f};
            s0 = MFMA(ka0, qb[i], s0);         // C[m=T0 row 4g+r][n=query s]
            s1 = MFMA(ka1, qb[i], s1);         // C[m=T1 row 4g+r][n=query s]
            bf16x8 pa;
            #pragma unroll
            for (int r = 0; r < 4; ++r) {
                pa[r]     = (__bf16)fast_exp2(s0[r]);
                pa[r + 4] = (__bf16)fast_exp2(s1[r]);
            }
            o[i][0] = MFMA(pa, vb0, o[i][0]);  // O[q=4g+r][d=s]
            o[i][1] = MFMA(pa, vb1, o[i][1]);  // d=16+s (row 24 ones -> denom at s=8)
        }
        __builtin_amdgcn_s_setprio(0);
        ka0 = nk0; ka1 = nk1; vb0 = nv0; vb1 = nv1;
    }

    // combine halves through LDS
    if (half) {
        #pragma unroll
        for (int i = 0; i < 5; ++i)
          #pragma unroll
          for (int j = 0; j < 2; ++j)
            #pragma unroll
            for (int r = 0; r < 4; ++r)
              red[tsk][i][j][r][lane] = o[i][j][r];
    }
    __syncthreads();
    if (!half) {
        #pragma unroll
        for (int i = 0; i < 5; ++i)
          #pragma unroll
          for (int j = 0; j < 2; ++j)
            #pragma unroll
            for (int r = 0; r < 4; ++r)
              o[i][j][r] += red[tsk][i][j][r][lane];

        int bw = wh / 3, h = wh % 3;
        int b = bw >> 5, w = bw & 31;
        unsigned* OWd = (unsigned*)OW;
        #pragma unroll
        for (int i = 0; i < 5; ++i) {
            #pragma unroll
            for (int r = 0; r < 4; ++r) {
                float den = __shfl(o[i][1][r], (lane & 48) + 8);   // ones-column
                float inv = 1.f / den;
                int n = w*WS_ + q0 + i*16 + g*4 + r;
                // OW phys col pair (h*32 + 2s, +1); den slot lands on zero woB row
                OWd[(size_t)(b*N_ + n)*48 + h*16 + s] =
                    pack_bf16(o[i][0][r]*inv, o[i][1][r]*inv);
            }
        }
    }
}

// ---------------- K4: MFMA tail + fused Highpass (wave = 16 rows, no inter-wave deps) ----------------
// Round-21-style row-split: m-dimension dropped -> per-wave serial MFMA chain halves
// (66 -> 33), waves 1600 -> 3200. LN2 stays wave-local; ZERO barriers, identical math.
__global__ __launch_bounds__(256) void k_tail(const float* __restrict__ seqT,
                                              const __bf16* __restrict__ OW,
                                              const __bf16* __restrict__ woB,
                                              const float* __restrict__ b_out,
                                              const float* __restrict__ g2,
                                              const float* __restrict__ b2,
                                              const __bf16* __restrict__ f1B,
                                              const float* __restrict__ fb1,
                                              const __bf16* __restrict__ f2B,
                                              const float* __restrict__ fb2,
                                              const __bf16* __restrict__ wfB,
                                              const float* __restrict__ bfin,
                                              float* __restrict__ out1,
                                              float* __restrict__ out2) {
    __shared__ __bf16 xfer[4][1024];           // 16 rows x 64 cols per wave, swizzled
    __shared__ float hp[4][16][49];            // Highpass staging, padded stride
    int t = threadIdx.x, wv = t>>6, lane = t&63, g = lane>>4, s = lane&15;
    int row0 = (blockIdx.x*4 + wv) * 16;       // 800 blocks x 4 waves x 16 rows
    char* xb = (char*)&xfer[wv][0];

    int b = row0 / N_;
    int nbase = row0 % N_;

    const bf16x8* OW4 = (const bf16x8*)OW;
    const bf16x8* WO4 = (const bf16x8*)woB;
    const bf16x8* F14 = (const bf16x8*)f1B;
    const bf16x8* F24 = (const bf16x8*)f2B;
    const bf16x8* WF4 = (const bf16x8*)wfB;

    // ---- S1: att = ow · w_out^T (k-dim in OW phys order) ----
    bf16x8 aow[3];
    #pragma unroll
    for (int kc = 0; kc < 3; ++kc)
        aow[kc] = OW4[(size_t)(row0 + s)*12 + kc*4 + g];

    f32x4 s2[3];
    __builtin_amdgcn_s_setprio(1);
    #pragma unroll
    for (int n = 0; n < 3; ++n) {
        bf16x8 wb0 = WO4[(n*16+s)*12 + g];
        bf16x8 wb1 = WO4[(n*16+s)*12 + 4 + g];
        bf16x8 wb2 = WO4[(n*16+s)*12 + 8 + g];
        f32x4 c = {0.f,0.f,0.f,0.f};
        c = MFMA(aow[0], wb0, c);
        c = MFMA(aow[1], wb1, c);
        c = MFMA(aow[2], wb2, c);
        s2[n] = c;
    }
    __builtin_amdgcn_s_setprio(0);
    float bov[3], g2v[3], b2v[3], f1bv[3], f2bv[3];
    #pragma unroll
    for (int n = 0; n < 3; ++n) {
        bov[n] = b_out[n*16+s]; g2v[n] = g2[n*16+s]; b2v[n] = b2[n*16+s];
        f1bv[n] = fb1[n*16+s];  f2bv[n] = fb2[n*16+s];
    }
    // keep raw seqT values for the fused Highpass
    float sv[3][4];
    #pragma unroll
    for (int n = 0; n < 3; ++n)
      #pragma unroll
      for (int r = 0; r < 4; ++r) {
        sv[n][r] = seqT[(size_t)(row0 + g*4 + r)*48 + n*16 + s];
        s2[n][r] += sv[n][r] + bov[n];
      }

    // ---- LN2 -> yn -> LDS ----
    #pragma unroll
    for (int r = 0; r < 4; ++r) {
        float sm = s2[0][r] + s2[1][r] + s2[2][r];
        float sq = s2[0][r]*s2[0][r] + s2[1][r]*s2[1][r] + s2[2][r]*s2[2][r];
        #pragma unroll
        for (int msk = 1; msk < 16; msk <<= 1) { sm += __shfl_xor(sm, msk); sq += __shfl_xor(sq, msk); }
        float mean = sm * (1.f/48.f);
        float var  = sq * (1.f/48.f) - mean*mean;
        float rs   = rsqrtf(var + 1e-5f);
        int row = g*4 + r;
        int sw  = (row&7) << 4;
        #pragma unroll
        for (int n = 0; n < 3; ++n) {
            float yn = (s2[n][r] - mean) * rs * g2v[n] + b2v[n];
            *(__bf16*)(xb + ((row*128 + (n*16+s)*2) ^ sw)) = (__bf16)yn;
        }
        *(__bf16*)(xb + ((row*128 + (48+s)*2) ^ sw)) = (__bf16)0.f;
    }

    bf16x8 af[2];
    f32x4 hh[3];

    // ---- ff1 ----
    #pragma unroll
    for (int kc = 0; kc < 2; ++kc)
        af[kc] = *(const bf16x8*)(xb + ((s*128 + kc*64 + g*16) ^ ((s&7)<<4)));
    __builtin_amdgcn_s_setprio(1);
    #pragma unroll
    for (int n = 0; n < 3; ++n) {
        bf16x8 wb0 = F14[(n*16+s)*8 + g];
        bf16x8 wb1 = F14[(n*16+s)*8 + 4 + g];
        f32x4 c = {0.f,0.f,0.f,0.f};
        c = MFMA(af[0], wb0, c);
        c = MFMA(af[1], wb1, c);
        hh[n] = c;
    }
    __builtin_amdgcn_s_setprio(0);
    #pragma unroll
    for (int r = 0; r < 4; ++r) {
        int row = g*4 + r;
        int sw  = (row&7) << 4;
        #pragma unroll
        for (int n = 0; n < 3; ++n) {
            float v = hh[n][r] + f1bv[n];
            v = v >= 0.f ? v : 0.01f*v;
            *(__bf16*)(xb + ((row*128 + (n*16+s)*2) ^ sw)) = (__bf16)v;
        }
        *(__bf16*)(xb + ((row*128 + (48+s)*2) ^ sw)) = (__bf16)0.f;
    }

    // ---- ff2 + residual -> a1 -> LDS; Highpass values -> hp staging ----
    #pragma unroll
    for (int kc = 0; kc < 2; ++kc)
        af[kc] = *(const bf16x8*)(xb + ((s*128 + kc*64 + g*16) ^ ((s&7)<<4)));
    __builtin_amdgcn_s_setprio(1);
    #pragma unroll
    for (int n = 0; n < 3; ++n) {
        bf16x8 wb0 = F24[(n*16+s)*8 + g];
        bf16x8 wb1 = F24[(n*16+s)*8 + 4 + g];
        f32x4 c = {0.f,0.f,0.f,0.f};
        c = MFMA(af[0], wb0, c);
        c = MFMA(af[1], wb1, c);
        hh[n] = c;
    }
    __builtin_amdgcn_s_setprio(0);
    #pragma unroll
    for (int r = 0; r < 4; ++r) {
        int row = g*4 + r;
        int sw  = (row&7) << 4;
        #pragma unroll
        for (int n = 0; n < 3; ++n) {
            float a1v = s2[n][r] + hh[n][r] + f2bv[n];
            hp[wv][row][n*16+s] = sv[n][r] * (1.f + a1v);
            *(__bf16*)(xb + ((row*128 + (n*16+s)*2) ^ sw)) = (__bf16)a1v;
        }
        *(__bf16*)(xb + ((row*128 + (48+s)*2) ^ sw)) = (__bf16)0.f;
    }

    // coalesced Highpass flush: out1[ch][nbase+row], 16B per lane (per-wave rows)
    #pragma unroll
    for (int it = 0; it < 3; ++it) {
        int flat = it*256 + lane*4;            // 0..764; flat = ch*16 + row
        int ch = flat >> 4, row = flat & 15;   // row % 4 == 0
        float4 v = { hp[wv][row][ch], hp[wv][row+1][ch],
                     hp[wv][row+2][ch], hp[wv][row+3][ch] };
        *(float4*)&out1[((size_t)b*D_ + ch)*N_ + nbase + row] = v;
    }

    // ---- final linear 48 -> 96 ----
    #pragma unroll
    for (int kc = 0; kc < 2; ++kc)
        af[kc] = *(const bf16x8*)(xb + ((s*128 + kc*64 + g*16) ^ ((s&7)<<4)));
    #pragma unroll
    for (int n = 0; n < 6; ++n) {
        bf16x8 wb0 = WF4[(n*16+s)*8 + g];
        bf16x8 wb1 = WF4[(n*16+s)*8 + 4 + g];
        float bfv = bfin[n*16+s];
        __builtin_amdgcn_s_setprio(1);
        f32x4 c = {0.f,0.f,0.f,0.f};
        c = MFMA(af[0], wb0, c);
        c = MFMA(af[1], wb1, c);
        __builtin_amdgcn_s_setprio(0);
        #pragma unroll
        for (int r = 0; r < 4; ++r)
            out2[(size_t)(row0 + g*4 + r)*96 + n*16 + s] = c[r] + bfv;
    }
}

extern "C" void kernel_launch(void* const* d_in, const int* in_sizes, int n_in,
                              void* d_out, int out_size, void* d_ws, size_t ws_size,
                              hipStream_t stream) {
    const float* x      = (const float*)d_in[0];
    const float* conv_w = (const float*)d_in[1];
    const float* conv_b = (const float*)d_in[2];
    const float* prelu_a= (const float*)d_in[3];
    const float* ln1_g  = (const float*)d_in[4];
    const float* ln1_b  = (const float*)d_in[5];
    const float* w_qkv  = (const float*)d_in[6];
    const float* E_mat  = (const float*)d_in[7];
    const float* F_mat  = (const float*)d_in[8];
    const float* w_e    = (const float*)d_in[9];
    const float* b_e    = (const float*)d_in[10];
    const float* w_f    = (const float*)d_in[11];
    const float* b_f    = (const float*)d_in[12];
    const float* w_out  = (const float*)d_in[13];
    const float* b_out  = (const float*)d_in[14];
    const float* ln2_g  = (const float*)d_in[15];
    const float* ln2_b  = (const float*)d_in[16];
    const float* ff_w1  = (const float*)d_in[17];
    const float* ff_b1  = (const float*)d_in[18];
    const float* ff_w2  = (const float*)d_in[19];
    const float* ff_b2  = (const float*)d_in[20];
    const float* w_fin  = (const float*)d_in[21];
    const float* b_fin  = (const float*)d_in[22];

    float* ws = (float*)d_ws;
    float*  seqT = ws;                                   // 2,457,600 f32
    float*  diag = seqT + (size_t)B_*N_*D_;              // 144 f32
    __bf16* Qbf  = (__bf16*)(diag + 144);                // 192*800*32 bf16 (d-interleaved)
    __bf16* Kbf  = Qbf + (size_t)NWH_*WS_*32;            // 192*800*32 bf16 (row-permuted, d-interleaved)
    __bf16* Vt   = Kbf + (size_t)NWH_*WS_*32;            // 192*32*800 bf16
    __bf16* OW   = Vt + (size_t)NWH_*32*WS_;             // 51200*96 bf16 (phys col order)
    __bf16* wqB  = OW + (size_t)B_*N_*96;                // 288*64
    __bf16* woB  = wqB + 288*64;                         // 48*96
    __bf16* f1B  = woB + 48*96;                          // 48*64
    __bf16* f2B  = f1B + 48*64;                          // 48*64
    __bf16* wfB  = f2B + 48*64;                          // 96*64
    __bf16* wcB  = wfB + 96*64;                          // 48*64

    float* out1 = (float*)d_out;               // [B,D,H,W]
    float* out2 = out1 + (size_t)B_*D_*N_;     // [B,N,96]

    k_wprep<<<32, 256, 0, stream>>>(w_qkv, w_out, ff_w1, ff_w2, w_fin, conv_w,
                                    E_mat, F_mat, w_e, b_e, w_f, b_f, diag,
                                    wqB, woB, f1B, f2B, wfB, wcB);
    k_cqkv<<<1600, 256, 0, stream>>>(x, wcB, conv_b, prelu_a,
                                     wqB, ln1_g, ln1_b, diag, seqT, Qbf, Kbf, Vt);
    k_attn<<<960, 256, 0, stream>>>(Qbf, Kbf, Vt, OW);
    k_tail<<<800, 256, 0, stream>>>(seqT, OW, woB, b_out, ln2_g, ln2_b,
                                    f1B, ff_b1, f2B, ff_b2, wfB, b_fin,
                                    out1, out2);
}

// Round 34
// 69.422 us; speedup vs baseline: 1.0662x; 1.0662x over previous
//
#include <hip/hip_runtime.h>
#include <hip/hip_bf16.h>

#define B_    2
#define CIN_  5
#define H_    160
#define W_    160
#define N_    25600        // H*W
#define D_    48
#define NW_   32
#define WS_   800
#define HEADS_ 3
#define DH_   24
#define INNER_ 72
#define NWH_  192          // B*NW*HEADS

typedef __bf16 bf16x8 __attribute__((ext_vector_type(8)));
typedef float  f32x4  __attribute__((ext_vector_type(4)));

#define MFMA(a,b,c) __builtin_amdgcn_mfma_f32_16x16x32_bf16((a),(b),(c),0,0,0)

__device__ __forceinline__ float fast_exp2(float x) {
#if __has_builtin(__builtin_amdgcn_exp2f)
    return __builtin_amdgcn_exp2f(x);
#else
    return exp2f(x);
#endif
}

__device__ __forceinline__ unsigned pack_bf16(float lo, float hi) {
    __bf16 l = (__bf16)lo, h = (__bf16)hi;
    unsigned short ul = __builtin_bit_cast(unsigned short, l);
    unsigned short uh = __builtin_bit_cast(unsigned short, h);
    return ((unsigned)uh << 16) | (unsigned)ul;
}

// ---------------- K0: weight prep -> padded/reordered bf16 (+ e/f diag) ----------------
__global__ __launch_bounds__(256) void k_wprep(const float* __restrict__ wqkv,
                                               const float* __restrict__ w_out,
                                               const float* __restrict__ fw1,
                                               const float* __restrict__ fw2,
                                               const float* __restrict__ wfin,
                                               const float* __restrict__ cw,
                                               const float* __restrict__ Em,
                                               const float* __restrict__ Fm,
                                               const float* __restrict__ we,
                                               const float* __restrict__ be,
                                               const float* __restrict__ wf,
                                               const float* __restrict__ bf,
                                               float* __restrict__ diag,
                                               __bf16* __restrict__ wqB,   // [288][64]
                                               __bf16* __restrict__ woB,   // [48][96]
                                               __bf16* __restrict__ f1B,   // [48][64]
                                               __bf16* __restrict__ f2B,   // [48][64]
                                               __bf16* __restrict__ wfB,   // [96][64]
                                               __bf16* __restrict__ wcB) { // [48][64]
    if (blockIdx.x == 0 && threadIdx.x < 72) {
        int tt = threadIdx.x;
        int h = tt / 24, d = tt % 24;
        float se = be[d], sf = bf[d];
        for (int w = 0; w < 30; ++w) {
            se += Em[(h*24+d)*30 + w] * we[d*30 + w];
            sf += Fm[(h*24+d)*30 + w] * wf[d*30 + w];
        }
        diag[tt]      = se;
        diag[72 + tt] = sf;
    }
    int t = blockIdx.x*256 + threadIdx.x, stride = gridDim.x*256;
    for (int i = t; i < 288*64; i += stride) {
        int grow = i>>6, c = i&63;
        int gg = grow>>5, q = grow&31, tt = q>>4, sp = q&15, d = tt*16+sp;
        int part = gg/3, head = gg%3;
        wqB[i] = (d<24 && c<48) ? (__bf16)wqkv[(head*72 + part*24 + d)*48 + c] : (__bf16)0.f;
    }
    for (int i = t; i < 48*96;  i += stride) {
        int o = i/96, p = i%96;
        int h = p>>5, q = p&31, j = q&1, sp = q>>1, d = j*16+sp;
        woB[i] = (d<24) ? (__bf16)w_out[o*72 + h*24 + d] : (__bf16)0.f;
    }
    for (int i = t; i < 48*64;  i += stride) { int o=i>>6, c=i&63; f1B[i] = (c<48)? (__bf16)fw1[o*48+c] : (__bf16)0.f; }
    for (int i = t; i < 48*64;  i += stride) { int o=i>>6, c=i&63; f2B[i] = (c<48)? (__bf16)fw2[o*48+c] : (__bf16)0.f; }
    for (int i = t; i < 96*64;  i += stride) { int o=i>>6, c=i&63; wfB[i] = (c<48)? (__bf16)wfin[o*48+c] : (__bf16)0.f; }
    for (int i = t; i < 48*64;  i += stride) { int o=i>>6, c=i&63; wcB[i] = (c<45)? (__bf16)cw[o*45+c] : (__bf16)0.f; }
}

// ---------------- K1: fused conv+LN1+QKV, 32-row blocks, 4-way group split ----------------
// 32 | 160 -> no image-row wrap: 3 halo rows, 34 guard cols (2 KB Lx), bounds-free gather.
// Waves 0-1: conv 16 rows each + LN. QKV: 9 groups over 4 waves (2/2/3/2).
// Pre-barrier: ALL waves issue first-group weight + diag loads (independent of conv);
// wave 3 also writes the constant Vt pad rows -> idle conv-phase waves do useful work.
__global__ __launch_bounds__(256) void k_cqkv(const float* __restrict__ x,
                                              const __bf16* __restrict__ wcB,
                                              const float* __restrict__ cb,
                                              const float* __restrict__ pa,
                                              const __bf16* __restrict__ wqB,
                                              const float* __restrict__ g1,
                                              const float* __restrict__ b1,
                                              const float* __restrict__ diag,
                                              float* __restrict__ seqT,
                                              __bf16* __restrict__ Qbf,
                                              __bf16* __restrict__ Kbf,
                                              __bf16* __restrict__ Vt) {
    __shared__ float Lx[CIN_][3][34];          // 2 KB: 3 halo rows, 32+2 guard cols
    __shared__ __bf16 xfer[32*64];             // 4 KB: 32 rows x 64 cols, swizzled
    int t = threadIdx.x;                       // 0..255
    int blk = blockIdx.x;                      // 0..1599
    int b = blk / 800;
    int n0 = (blk % 800) * 32;                 // pixel index within image
    int y0 = n0 / W_;                          // exact row (no wrap: 32 | 160)
    int x0 = n0 % W_;

    // ---- cooperative x staging: rows y0-1..y0+1, cols x0-1..x0+32, zeros outside ----
    for (int i = t; i < CIN_*3*34; i += 256) {
        int ic = i / (3*34), rem = i % (3*34), yy = rem / 34, col = rem % 34;
        int yr = y0 - 1 + yy;
        int xc = x0 - 1 + col;
        float v = 0.f;
        if (yr >= 0 && yr < H_ && xc >= 0 && xc < W_)
            v = x[((size_t)(b*CIN_ + ic)*H_ + yr)*W_ + xc];
        Lx[ic][yy][col] = v;
    }

    int wv = t >> 6, lane = t & 63, g = lane>>4, s = lane&15;
    char* xb = (char*)xfer;

    // ---- pre-barrier: QKV-phase setup, independent of conv ----
    int w = n0 / WS_, i0 = n0 % WS_;           // 32 | 800: block stays in one window
    size_t headbase = (size_t)((b*NW_ + w)*HEADS_);
    const bf16x8* WQ4 = (const bf16x8*)wqB;
    int gg0 = (wv < 3) ? wv*2 : 7;
    int gg1 = (wv == 2) ? 7 : gg0 + 2;
    // first-group weights in flight during conv phase
    bf16x8 we0 = WQ4[(gg0*32 +      s)*8 +     g];
    bf16x8 we1 = WQ4[(gg0*32 +      s)*8 + 4 + g];
    bf16x8 wo0 = WQ4[(gg0*32 + 16 + s)*8 +     g];
    bf16x8 wo1 = WQ4[(gg0*32 + 16 + s)*8 + 4 + g];
    float dke[3], dko[3], dve[3], dvo[3];
    #pragma unroll
    for (int h = 0; h < 3; ++h) {
        dke[h] = diag[h*24 + s];
        dko[h] = (s < 8) ? diag[h*24 + 16 + s] : 0.f;
        dve[h] = diag[72 + h*24 + s];
        dvo[h] = (s < 8) ? diag[72 + h*24 + 16 + s] : 0.f;
    }
    // Vt pad rows 24..31 (ones at 24): wave 3, overlapped with conv phase
    if (wv == 3) {
        unsigned* Vd = (unsigned*)Vt;
        #pragma unroll
        for (int it = 0; it < 6; ++it) {
            int idx = it*64 + lane;           // 0..383
            int h = idx >> 7, rem = idx & 127;
            int dd = 24 + (rem >> 4), cp = rem & 15;
            size_t ubase = (((headbase + h)*((size_t)32*WS_) + (size_t)dd*WS_ + i0) >> 1);
            Vd[ubase + cp] = (dd == 24) ? 0x3F803F80u : 0u;
        }
    }
    __syncthreads();                           // Lx ready

    // ---- conv phase: waves 0-1 own 16 rows each; waves 2-3 wait ----
    if (wv < 2) {
        int rloc0 = wv * 16;
        int rib = rloc0 + s;                   // row in block = pixel offset
        bf16x8 ac[2];
        #pragma unroll
        for (int kc = 0; kc < 2; ++kc) {
            int kbase = kc*32 + g*8;
            #pragma unroll
            for (int j = 0; j < 8; ++j) {
                int k = kbase + j;
                int ic = k / 9, rem = k % 9, ky = rem / 3, kx = rem % 3;
                float v = 0.f;
                if (kc == 0 || k < 45)
                    v = Lx[ic][ky][rib + kx];  // guard cols absorb edges
                ac[kc][j] = (__bf16)v;
            }
        }
        const bf16x8* WC4 = (const bf16x8*)wcB;
        float a = pa[0];
        float cbv[3], g1v[3], b1v[3];
        #pragma unroll
        for (int n = 0; n < 3; ++n) {
            cbv[n] = cb[n*16+s]; g1v[n] = g1[n*16+s]; b1v[n] = b1[n*16+s];
        }
        float xr[3][4];
        #pragma unroll
        for (int n = 0; n < 3; ++n) {
            bf16x8 wb0 = WC4[(n*16+s)*8 + g];
            bf16x8 wb1 = WC4[(n*16+s)*8 + 4 + g];
            f32x4 c = {0.f,0.f,0.f,0.f};
            c = MFMA(ac[0], wb0, c);
            c = MFMA(ac[1], wb1, c);
            #pragma unroll
            for (int r = 0; r < 4; ++r) {
                float vv = c[r] + cbv[n];
                vv = vv >= 0.f ? vv : a * vv;
                xr[n][r] = vv;
            }
        }
        int grow0 = blk*32 + rloc0;
        #pragma unroll
        for (int n = 0; n < 3; ++n)
          #pragma unroll
          for (int r = 0; r < 4; ++r)
            seqT[(size_t)(grow0 + g*4 + r)*48 + n*16 + s] = xr[n][r];

        // LN per row -> xfer (swizzled); row&7 == (g*4+r)&7 since rloc0 % 16 == 0
        #pragma unroll
        for (int r = 0; r < 4; ++r) {
            float sm = xr[0][r] + xr[1][r] + xr[2][r];
            float sq = xr[0][r]*xr[0][r] + xr[1][r]*xr[1][r] + xr[2][r]*xr[2][r];
            #pragma unroll
            for (int msk = 1; msk < 16; msk <<= 1) { sm += __shfl_xor(sm, msk); sq += __shfl_xor(sq, msk); }
            float mean = sm * (1.f/48.f);
            float var  = sq * (1.f/48.f) - mean*mean;
            float rs   = rsqrtf(var + 1e-5f);
            int row = rloc0 + g*4 + r;
            int sw  = ((g*4+r)&7) << 4;
            #pragma unroll
            for (int n = 0; n < 3; ++n) {
                float yn = (xr[n][r] - mean) * rs * g1v[n] + b1v[n];
                *(__bf16*)(xb + ((row*128 + (n*16+s)*2) ^ sw)) = (__bf16)yn;
            }
            *(__bf16*)(xb + ((row*128 + (48+s)*2) ^ sw)) = (__bf16)0.f;  // K-pad
        }
    }
    __syncthreads();

    // ---- QKV phase: 9 groups over 4 waves: {0,1} {2,3} {4,5,6} {7,8} ----
    bf16x8 af[2][2];
    #pragma unroll
    for (int m = 0; m < 2; ++m)
      #pragma unroll
      for (int kc = 0; kc < 2; ++kc) {
        int row = m*16 + s;
        af[m][kc] = *(const bf16x8*)(xb + ((row*128 + kc*64 + g*16) ^ ((s&7)<<4)));
      }

    // 24^-0.5 * log2(e): fold attention scale AND exp2 conversion into Q
    const float SCALE = 0.2944889919f;

    unsigned* Qd = (unsigned*)Qbf;
    unsigned* Kd = (unsigned*)Kbf;

    for (int gg = gg0; gg < gg1; ++gg) {
        int part = gg / 3, head = gg % 3;
        if (gg != gg0) {                       // first group preloaded pre-barrier
            we0 = WQ4[(gg*32 +      s)*8 +     g];
            we1 = WQ4[(gg*32 +      s)*8 + 4 + g];
            wo0 = WQ4[(gg*32 + 16 + s)*8 +     g];
            wo1 = WQ4[(gg*32 + 16 + s)*8 + 4 + g];
        }
        f32x4 ce[2], co[2];
        __builtin_amdgcn_s_setprio(1);
        #pragma unroll
        for (int m = 0; m < 2; ++m) {
            f32x4 c = {0.f,0.f,0.f,0.f};
            c = MFMA(af[m][0], we0, c); c = MFMA(af[m][1], we1, c);
            ce[m] = c;
            f32x4 d = {0.f,0.f,0.f,0.f};
            d = MFMA(af[m][0], wo0, d); d = MFMA(af[m][1], wo1, d);
            co[m] = d;
        }
        __builtin_amdgcn_s_setprio(0);
        size_t rbase = (headbase + head)*WS_ + i0;
        if (part == 0) {
            #pragma unroll
            for (int m = 0; m < 2; ++m)
              #pragma unroll
              for (int r = 0; r < 4; ++r)
                Qd[(rbase + m*16 + g*4 + r)*16 + s] =
                    pack_bf16(ce[m][r]*SCALE, co[m][r]*SCALE);
        } else if (part == 1) {
            #pragma unroll
            for (int m = 0; m < 2; ++m)
              #pragma unroll
              for (int r = 0; r < 4; ++r) {
                int p5 = 16*(g&1) + 8*m + 4*(g>>1) + r;
                Kd[(rbase + p5)*16 + s] =
                    pack_bf16(ce[m][r]*dke[head], co[m][r]*dko[head]);
              }
        } else {
            // V: each lane's 4 r-values are CONSECUTIVE in Vt's n-dim -> one 8B store
            size_t vbase = (headbase + head)*((size_t)32*WS_) + i0;
            #pragma unroll
            for (int m = 0; m < 2; ++m) {
                uint2 pe;
                pe.x = pack_bf16(ce[m][0]*dve[head], ce[m][1]*dve[head]);
                pe.y = pack_bf16(ce[m][2]*dve[head], ce[m][3]*dve[head]);
                *(uint2*)&Vt[vbase + (size_t)s*WS_ + m*16 + g*4] = pe;
                if (s < 8) {
                    uint2 po;
                    po.x = pack_bf16(co[m][0]*dvo[head], co[m][1]*dvo[head]);
                    po.y = pack_bf16(co[m][2]*dvo[head], co[m][3]*dvo[head]);
                    *(uint2*)&Vt[vbase + (size_t)(16+s)*WS_ + m*16 + g*4] = po;
                }
            }
        }
    }
}

// ---------------- K3: MFMA attention, register-resident P, split-K wave pairs ----------------
// 2-way split + bijective XCD-chunked block swizzle + setprio around MFMA cluster (T5).
__global__ __launch_bounds__(256, 4) void k_attn(const __bf16* __restrict__ Qbf,
                                                 const __bf16* __restrict__ Kbf,
                                                 const __bf16* __restrict__ Vt,
                                                 __bf16* __restrict__ OW) {
    __shared__ float red[2][5][2][4][64];      // 20 KB
    int t = threadIdx.x;
    int wv = t >> 6, lane = t & 63;
    int g = lane >> 4, s = lane & 15;
    int half = wv & 1, tsk = wv >> 1;
    int blk = blockIdx.x;                      // 0..959
    int v = (blk & 7) * 120 + (blk >> 3);      // XCD-chunked bijection
    int task = v * 2 + tsk;                    // 0..1919 exactly
    int wh = task / 10, qt = task % 10;
    int q0 = qt * 80;

    const bf16x8* Qp = (const bf16x8*)(Qbf + ((size_t)wh*WS_ + q0)*32);
    const bf16x8* Kp = (const bf16x8*)(Kbf + (size_t)wh*WS_*32);
    const bf16x8* Vp = (const bf16x8*)(Vt  + (size_t)wh*32*WS_);

    // Q as B-operand: col = query = lane&15
    bf16x8 qb[5];
    #pragma unroll
    for (int i = 0; i < 5; ++i) qb[i] = Qp[(i*16 + s)*4 + g];

    f32x4 o[5][2];
    #pragma unroll
    for (int i = 0; i < 5; ++i) {
        o[i][0] = (f32x4){0.f,0.f,0.f,0.f};
        o[i][1] = (f32x4){0.f,0.f,0.f,0.f};
    }

    // combining wave (half 0) gets one chunk less: 12 vs 13
    int c0 = half ? 12 : 0;
    int c1 = half ? 25 : 12;

    // prefetch first chunk
    bf16x8 ka0 = Kp[(c0*32 + s)*4 + g];
    bf16x8 ka1 = Kp[(c0*32 + 16 + s)*4 + g];
    bf16x8 vb0 = Vp[s*100 + c0*4 + g];
    bf16x8 vb1 = Vp[(16+s)*100 + c0*4 + g];

    for (int c = c0; c < c1; ++c) {
        int cn = (c + 1 < c1) ? c + 1 : c0;    // last-iter reload is harmless
        bf16x8 nk0 = Kp[(cn*32 + s)*4 + g];
        bf16x8 nk1 = Kp[(cn*32 + 16 + s)*4 + g];
        bf16x8 nv0 = Vp[s*100 + cn*4 + g];
        bf16x8 nv1 = Vp[(16+s)*100 + cn*4 + g];

        __builtin_amdgcn_s_setprio(1);
        #pragma unroll
        for (int i = 0; i < 5; ++i) {
            f32x4 s0 = {0.f,0.f,0.f,0.f}, s1 = {0.f,0.f,0.f,0.f};
            s0 = MFMA(ka0, qb[i], s0);         // C[m=T0 row 4g+r][n=query s]
            s1 = MFMA(ka1, qb[i], s1);         // C[m=T1 row 4g+r][n=query s]
            bf16x8 pa;
            #pragma unroll
            for (int r = 0; r < 4; ++r) {
                pa[r]     = (__bf16)fast_exp2(s0[r]);
                pa[r + 4] = (__bf16)fast_exp2(s1[r]);
            }
            o[i][0] = MFMA(pa, vb0, o[i][0]);  // O[q=4g+r][d=s]
            o[i][1] = MFMA(pa, vb1, o[i][1]);  // d=16+s (row 24 ones -> denom at s=8)
        }
        __builtin_amdgcn_s_setprio(0);
        ka0 = nk0; ka1 = nk1; vb0 = nv0; vb1 = nv1;
    }

    // combine halves through LDS
    if (half) {
        #pragma unroll
        for (int i = 0; i < 5; ++i)
          #pragma unroll
          for (int j = 0; j < 2; ++j)
            #pragma unroll
            for (int r = 0; r < 4; ++r)
              red[tsk][i][j][r][lane] = o[i][j][r];
    }
    __syncthreads();
    if (!half) {
        #pragma unroll
        for (int i = 0; i < 5; ++i)
          #pragma unroll
          for (int j = 0; j < 2; ++j)
            #pragma unroll
            for (int r = 0; r < 4; ++r)
              o[i][j][r] += red[tsk][i][j][r][lane];

        int bw = wh / 3, h = wh % 3;
        int b = bw >> 5, w = bw & 31;
        unsigned* OWd = (unsigned*)OW;
        #pragma unroll
        for (int i = 0; i < 5; ++i) {
            #pragma unroll
            for (int r = 0; r < 4; ++r) {
                float den = __shfl(o[i][1][r], (lane & 48) + 8);   // ones-column
                float inv = 1.f / den;
                int n = w*WS_ + q0 + i*16 + g*4 + r;
                // OW phys col pair (h*32 + 2s, +1); den slot lands on zero woB row
                OWd[(size_t)(b*N_ + n)*48 + h*16 + s] =
                    pack_bf16(o[i][0][r]*inv, o[i][1][r]*inv);
            }
        }
    }
}

// ---------------- K4: MFMA tail + fused Highpass (wave = 32 rows) ----------------
__global__ __launch_bounds__(256) void k_tail(const float* __restrict__ seqT,
                                              const __bf16* __restrict__ OW,
                                              const __bf16* __restrict__ woB,
                                              const float* __restrict__ b_out,
                                              const float* __restrict__ g2,
                                              const float* __restrict__ b2,
                                              const __bf16* __restrict__ f1B,
                                              const float* __restrict__ fb1,
                                              const __bf16* __restrict__ f2B,
                                              const float* __restrict__ fb2,
                                              const __bf16* __restrict__ wfB,
                                              const float* __restrict__ bfin,
                                              float* __restrict__ out1,
                                              float* __restrict__ out2) {
    __shared__ __bf16 xfer[4][2048];
    __shared__ float hp[4][32][49];            // Highpass staging, padded stride
    int t = threadIdx.x, wv = t>>6, lane = t&63, g = lane>>4, s = lane&15;
    int row0 = (blockIdx.x*4 + wv) * 32;
    char* xb = (char*)&xfer[wv][0];

    int b = row0 / N_;
    int nbase = row0 % N_;

    const bf16x8* OW4 = (const bf16x8*)OW;
    const bf16x8* WO4 = (const bf16x8*)woB;
    const bf16x8* F14 = (const bf16x8*)f1B;
    const bf16x8* F24 = (const bf16x8*)f2B;
    const bf16x8* WF4 = (const bf16x8*)wfB;

    // ---- S1: att = ow · w_out^T (k-dim in OW phys order) ----
    bf16x8 aow[2][3];
    #pragma unroll
    for (int m = 0; m < 2; ++m)
      #pragma unroll
      for (int kc = 0; kc < 3; ++kc)
        aow[m][kc] = OW4[(size_t)(row0 + m*16 + s)*12 + kc*4 + g];

    f32x4 s2[2][3];
    __builtin_amdgcn_s_setprio(1);
    #pragma unroll
    for (int n = 0; n < 3; ++n) {
        bf16x8 wb0 = WO4[(n*16+s)*12 + g];
        bf16x8 wb1 = WO4[(n*16+s)*12 + 4 + g];
        bf16x8 wb2 = WO4[(n*16+s)*12 + 8 + g];
        #pragma unroll
        for (int m = 0; m < 2; ++m) {
            f32x4 c = {0.f,0.f,0.f,0.f};
            c = MFMA(aow[m][0], wb0, c);
            c = MFMA(aow[m][1], wb1, c);
            c = MFMA(aow[m][2], wb2, c);
            s2[m][n] = c;
        }
    }
    __builtin_amdgcn_s_setprio(0);
    float bov[3], g2v[3], b2v[3], f1bv[3], f2bv[3];
    #pragma unroll
    for (int n = 0; n < 3; ++n) {
        bov[n] = b_out[n*16+s]; g2v[n] = g2[n*16+s]; b2v[n] = b2[n*16+s];
        f1bv[n] = fb1[n*16+s];  f2bv[n] = fb2[n*16+s];
    }
    // keep raw seqT values for the fused Highpass
    float sv[2][3][4];
    #pragma unroll
    for (int m = 0; m < 2; ++m)
      #pragma unroll
      for (int n = 0; n < 3; ++n)
        #pragma unroll
        for (int r = 0; r < 4; ++r) {
          sv[m][n][r] = seqT[(size_t)(row0 + m*16 + g*4 + r)*48 + n*16 + s];
          s2[m][n][r] += sv[m][n][r] + bov[n];
        }

    // ---- LN2 -> yn -> LDS ----
    #pragma unroll
    for (int m = 0; m < 2; ++m)
      #pragma unroll
      for (int r = 0; r < 4; ++r) {
        float sm = s2[m][0][r] + s2[m][1][r] + s2[m][2][r];
        float sq = s2[m][0][r]*s2[m][0][r] + s2[m][1][r]*s2[m][1][r] + s2[m][2][r]*s2[m][2][r];
        #pragma unroll
        for (int msk = 1; msk < 16; msk <<= 1) { sm += __shfl_xor(sm, msk); sq += __shfl_xor(sq, msk); }
        float mean = sm * (1.f/48.f);
        float var  = sq * (1.f/48.f) - mean*mean;
        float rs   = rsqrtf(var + 1e-5f);
        int row = m*16 + g*4 + r;
        int sw  = ((g*4+r)&7) << 4;
        #pragma unroll
        for (int n = 0; n < 3; ++n) {
            float yn = (s2[m][n][r] - mean) * rs * g2v[n] + b2v[n];
            *(__bf16*)(xb + ((row*128 + (n*16+s)*2) ^ sw)) = (__bf16)yn;
        }
        *(__bf16*)(xb + ((row*128 + (48+s)*2) ^ sw)) = (__bf16)0.f;
      }

    bf16x8 af[2][2];
    f32x4 hh[2][3];

    // ---- ff1 ----
    #pragma unroll
    for (int m = 0; m < 2; ++m)
      #pragma unroll
      for (int kc = 0; kc < 2; ++kc)
        af[m][kc] = *(const bf16x8*)(xb + (((m*16+s)*128 + kc*64 + g*16) ^ ((s&7)<<4)));
    __builtin_amdgcn_s_setprio(1);
    #pragma unroll
    for (int n = 0; n < 3; ++n) {
        bf16x8 wb0 = F14[(n*16+s)*8 + g];
        bf16x8 wb1 = F14[(n*16+s)*8 + 4 + g];
        #pragma unroll
        for (int m = 0; m < 2; ++m) {
            f32x4 c = {0.f,0.f,0.f,0.f};
            c = MFMA(af[m][0], wb0, c);
            c = MFMA(af[m][1], wb1, c);
            hh[m][n] = c;
        }
    }
    __builtin_amdgcn_s_setprio(0);
    #pragma unroll
    for (int m = 0; m < 2; ++m)
      #pragma unroll
      for (int r = 0; r < 4; ++r) {
        int row = m*16 + g*4 + r;
        int sw  = ((g*4+r)&7) << 4;
        #pragma unroll
        for (int n = 0; n < 3; ++n) {
            float v = hh[m][n][r] + f1bv[n];
            v = v >= 0.f ? v : 0.01f*v;
            *(__bf16*)(xb + ((row*128 + (n*16+s)*2) ^ sw)) = (__bf16)v;
        }
        *(__bf16*)(xb + ((row*128 + (48+s)*2) ^ sw)) = (__bf16)0.f;
      }

    // ---- ff2 + residual -> a1 -> LDS; Highpass values -> hp staging ----
    #pragma unroll
    for (int m = 0; m < 2; ++m)
      #pragma unroll
      for (int kc = 0; kc < 2; ++kc)
        af[m][kc] = *(const bf16x8*)(xb + (((m*16+s)*128 + kc*64 + g*16) ^ ((s&7)<<4)));
    __builtin_amdgcn_s_setprio(1);
    #pragma unroll
    for (int n = 0; n < 3; ++n) {
        bf16x8 wb0 = F24[(n*16+s)*8 + g];
        bf16x8 wb1 = F24[(n*16+s)*8 + 4 + g];
        #pragma unroll
        for (int m = 0; m < 2; ++m) {
            f32x4 c = {0.f,0.f,0.f,0.f};
            c = MFMA(af[m][0], wb0, c);
            c = MFMA(af[m][1], wb1, c);
            hh[m][n] = c;
        }
    }
    __builtin_amdgcn_s_setprio(0);
    #pragma unroll
    for (int m = 0; m < 2; ++m)
      #pragma unroll
      for (int r = 0; r < 4; ++r) {
        int row = m*16 + g*4 + r;
        int sw  = ((g*4+r)&7) << 4;
        #pragma unroll
        for (int n = 0; n < 3; ++n) {
            float a1v = s2[m][n][r] + hh[m][n][r] + f2bv[n];
            hp[wv][row][n*16+s] = sv[m][n][r] * (1.f + a1v);
            *(__bf16*)(xb + ((row*128 + (n*16+s)*2) ^ sw)) = (__bf16)a1v;
        }
        *(__bf16*)(xb + ((row*128 + (48+s)*2) ^ sw)) = (__bf16)0.f;
      }

    // coalesced Highpass flush: out1[ch][nbase+row], 16B per lane
    #pragma unroll
    for (int it = 0; it < 6; ++it) {
        int flat = it*256 + lane*4;
        int ch = flat >> 5, row = flat & 31;
        float4 v = { hp[wv][row][ch], hp[wv][row+1][ch],
                     hp[wv][row+2][ch], hp[wv][row+3][ch] };
        *(float4*)&out1[((size_t)b*D_ + ch)*N_ + nbase + row] = v;
    }

    // ---- final linear 48 -> 96 ----
    #pragma unroll
    for (int m = 0; m < 2; ++m)
      #pragma unroll
      for (int kc = 0; kc < 2; ++kc)
        af[m][kc] = *(const bf16x8*)(xb + (((m*16+s)*128 + kc*64 + g*16) ^ ((s&7)<<4)));
    #pragma unroll
    for (int n = 0; n < 6; ++n) {
        bf16x8 wb0 = WF4[(n*16+s)*8 + g];
        bf16x8 wb1 = WF4[(n*16+s)*8 + 4 + g];
        float bfv = bfin[n*16+s];
        __builtin_amdgcn_s_setprio(1);
        f32x4 cc[2];
        #pragma unroll
        for (int m = 0; m < 2; ++m) {
            f32x4 c = {0.f,0.f,0.f,0.f};
            c = MFMA(af[m][0], wb0, c);
            c = MFMA(af[m][1], wb1, c);
            cc[m] = c;
        }
        __builtin_amdgcn_s_setprio(0);
        #pragma unroll
        for (int m = 0; m < 2; ++m)
          #pragma unroll
          for (int r = 0; r < 4; ++r)
            out2[(size_t)(row0 + m*16 + g*4 + r)*96 + n*16 + s] = cc[m][r] + bfv;
    }
}

extern "C" void kernel_launch(void* const* d_in, const int* in_sizes, int n_in,
                              void* d_out, int out_size, void* d_ws, size_t ws_size,
                              hipStream_t stream) {
    const float* x      = (const float*)d_in[0];
    const float* conv_w = (const float*)d_in[1];
    const float* conv_b = (const float*)d_in[2];
    const float* prelu_a= (const float*)d_in[3];
    const float* ln1_g  = (const float*)d_in[4];
    const float* ln1_b  = (const float*)d_in[5];
    const float* w_qkv  = (const float*)d_in[6];
    const float* E_mat  = (const float*)d_in[7];
    const float* F_mat  = (const float*)d_in[8];
    const float* w_e    = (const float*)d_in[9];
    const float* b_e    = (const float*)d_in[10];
    const float* w_f    = (const float*)d_in[11];
    const float* b_f    = (const float*)d_in[12];
    const float* w_out  = (const float*)d_in[13];
    const float* b_out  = (const float*)d_in[14];
    const float* ln2_g  = (const float*)d_in[15];
    const float* ln2_b  = (const float*)d_in[16];
    const float* ff_w1  = (const float*)d_in[17];
    const float* ff_b1  = (const float*)d_in[18];
    const float* ff_w2  = (const float*)d_in[19];
    const float* ff_b2  = (const float*)d_in[20];
    const float* w_fin  = (const float*)d_in[21];
    const float* b_fin  = (const float*)d_in[22];

    float* ws = (float*)d_ws;
    float*  seqT = ws;                                   // 2,457,600 f32
    float*  diag = seqT + (size_t)B_*N_*D_;              // 144 f32
    __bf16* Qbf  = (__bf16*)(diag + 144);                // 192*800*32 bf16 (d-interleaved)
    __bf16* Kbf  = Qbf + (size_t)NWH_*WS_*32;            // 192*800*32 bf16 (row-permuted, d-interleaved)
    __bf16* Vt   = Kbf + (size_t)NWH_*WS_*32;            // 192*32*800 bf16
    __bf16* OW   = Vt + (size_t)NWH_*32*WS_;             // 51200*96 bf16 (phys col order)
    __bf16* wqB  = OW + (size_t)B_*N_*96;                // 288*64
    __bf16* woB  = wqB + 288*64;                         // 48*96
    __bf16* f1B  = woB + 48*96;                          // 48*64
    __bf16* f2B  = f1B + 48*64;                          // 48*64
    __bf16* wfB  = f2B + 48*64;                          // 96*64
    __bf16* wcB  = wfB + 96*64;                          // 48*64

    float* out1 = (float*)d_out;               // [B,D,H,W]
    float* out2 = out1 + (size_t)B_*D_*N_;     // [B,N,96]

    k_wprep<<<32, 256, 0, stream>>>(w_qkv, w_out, ff_w1, ff_w2, w_fin, conv_w,
                                    E_mat, F_mat, w_e, b_e, w_f, b_f, diag,
                                    wqB, woB, f1B, f2B, wfB, wcB);
    k_cqkv<<<1600, 256, 0, stream>>>(x, wcB, conv_b, prelu_a,
                                     wqB, ln1_g, ln1_b, diag, seqT, Qbf, Kbf, Vt);
    k_attn<<<960, 256, 0, stream>>>(Qbf, Kbf, Vt, OW);
    k_tail<<<400, 256, 0, stream>>>(seqT, OW, woB, b_out, ln2_g, ln2_b,
                                    f1B, ff_b1, f2B, ff_b2, wfB, b_fin,
                                    out1, out2);
}